// Round 18
// baseline (5256.474 us; speedup 1.0000x reference)
//
#include <hip/hip_runtime.h>
#include <hip/hip_bf16.h>
#include <math.h>

// Workspace (f32):
//  ua 0 / ua_ 16777216 / ub 33554432 / ub_ 34603008 / GTa 35651584
//  GTb 37748736 / coef 38273024 / coef2 38535168 / t512 38797312 ; end 38798336

__device__ __forceinline__ float gelu_f(float x) {
  float t = tanhf(0.7978845608028654f * (x + 0.044715f * x * x * x));
  return 0.5f * x * (1.0f + t);
}

__global__ void ktab(float2* __restrict__ t512) {
  int k = blockIdx.x * 256 + threadIdx.x;
  if (k < 512) {
    float a = (float)((double)k * (6.283185307179586 / 512.0));
    t512[k] = make_float2(cosf(a), sinf(a));
  }
}

template <int HW>
__global__ __launch_bounds__(256) void kenc(const float* __restrict__ xin,
                                            const float* __restrict__ uin,
                                            const float* __restrict__ w,
                                            const float* __restrict__ b,
                                            float* __restrict__ out) {
  int p = blockIdx.x * 256 + threadIdx.x;
  float i0 = xin[p], i1 = xin[HW + p];
  float i2 = uin[p], i3 = uin[HW + p];
  for (int c = 0; c < 64; ++c)
    out[(size_t)c * HW + p] =
        w[c * 4 + 0] * i0 + w[c * 4 + 1] * i1 + w[c * 4 + 2] * i2 + w[c * 4 + 3] * i3 + b[c];
}

template <int H, int LOG2H, int MUL>
__global__ __launch_bounds__(256) void kfwd1(const float* __restrict__ x, float2* __restrict__ G,
                                             const float2* __restrict__ tw, float fs) {
  int idx = blockIdx.x * 256 + threadIdx.x;
  int h = idx & (H - 1);
  int kc = (idx >> LOG2H) & 31;
  int c = idx >> (LOG2H + 5);
  const float* xr = x + ((size_t)c * H + h) * H;
  float re = 0.f, im = 0.f;
  for (int w = 0; w < H; ++w) {
    float xv = xr[w];
    float2 e = tw[(w * kc * MUL) & 511];
    re = fmaf(xv, e.x, re);
    im = fmaf(-xv, e.y, im);
  }
  G[((size_t)c * 32 + kc) * H + h] = make_float2(re * fs, im * fs);
}

template <int H, int MUL>
__global__ __launch_bounds__(256) void kfwd2(const float2* __restrict__ G, float2* __restrict__ coeff,
                                             const float2* __restrict__ tw, int cbase) {
  int idx = blockIdx.x * 256 + threadIdx.x;
  int kc = idx & 31;
  int jr = (idx >> 5) & 31;
  int c = idx >> 10;
  const float2* gr = G + ((size_t)c * 32 + kc) * H;
  int f = jr - 16;
  float re = 0.f, im = 0.f;
  for (int h = 0; h < H; ++h) {
    float2 g = gr[h];
    float2 e = tw[(f * h * MUL) & 511];
    re += g.x * e.x + g.y * e.y;
    im += g.y * e.x - g.x * e.y;
  }
  coeff[(size_t)(cbase + c) * 1024 + jr * 32 + kc] = make_float2(re, im);
}

__global__ __launch_bounds__(256) void kmix(const float* __restrict__ Are,
                                            const float* __restrict__ Aim,
                                            const float2* __restrict__ cin,
                                            float2* __restrict__ cout) {
  int idx = blockIdx.x * 256 + threadIdx.x;
  int mn = idx & 1023;
  int o = idx >> 10;
  const float* ar = Are + (size_t)o * 131072 + mn;
  const float* ai = Aim + (size_t)o * 131072 + mn;
  float re = 0.f, im = 0.f;
  for (int i = 0; i < 128; ++i) {
    float wr = ar[(size_t)i * 1024];
    float wi = ai[(size_t)i * 1024];
    float2 x = cin[(size_t)i * 1024 + mn];
    re += wr * x.x - wi * x.y;
    im += wr * x.y + wi * x.x;
  }
  cout[(size_t)o * 1024 + mn] = make_float2(re, im);
}

template <int H, int LOG2H, int MUL>
__global__ __launch_bounds__(256) void kinv1(const float2* __restrict__ coeff, float2* __restrict__ T,
                                             const float2* __restrict__ tw, int cbase) {
  int idx = blockIdx.x * 256 + threadIdx.x;
  int kc = idx & 31;
  int h = (idx >> 5) & (H - 1);
  int c = idx >> (5 + LOG2H);
  float re = 0.f, im = 0.f;
  for (int jr = 0; jr < 32; ++jr) {
    float2 x = coeff[(size_t)(cbase + c) * 1024 + jr * 32 + kc];
    float2 e = tw[((jr - 16) * h * MUL) & 511];
    re += x.x * e.x - x.y * e.y;
    im += x.x * e.y + x.y * e.x;
  }
  float wgt = (kc == 0) ? 1.f : 2.f;
  T[((size_t)c * H + h) * 32 + kc] = make_float2(re * wgt, im * wgt);
}

template <int H, int LOG2H, int MUL>
__global__ __launch_bounds__(256) void kinv2(const float2* __restrict__ T, float* __restrict__ out,
                                             const float2* __restrict__ tw) {
  int idx = blockIdx.x * 256 + threadIdx.x;
  int w = idx & (H - 1);
  int h = (idx >> LOG2H) & (H - 1);
  int c = idx >> (2 * LOG2H);
  const float2* tr = T + ((size_t)c * H + h) * 32;
  float acc = 0.f;
  for (int kc = 0; kc < 32; ++kc) {
    float2 t = tr[kc];
    float2 e = tw[(kc * w * MUL) & 511];
    acc += t.x * e.x - t.y * e.y;
  }
  out[((size_t)c * H + h) * H + w] = acc;
}

template <int HW>
__global__ __launch_bounds__(256) void kconv(const float* __restrict__ xin, float* __restrict__ uio,
                                             const float* __restrict__ w1, const float* __restrict__ b1,
                                             const float* __restrict__ w2, const float* __restrict__ b2) {
  int p = blockIdx.x * 256 + threadIdx.x;
  float v[64];
#pragma unroll
  for (int o = 0; o < 64; ++o) v[o] = b1[o];
  for (int ci = 0; ci < 64; ++ci) {
    float xv = xin[(size_t)ci * HW + p];
#pragma unroll
    for (int o = 0; o < 64; ++o) v[o] = fmaf(w1[o * 64 + ci], xv, v[o]);
  }
#pragma unroll
  for (int o = 0; o < 64; ++o) v[o] = gelu_f(v[o]);
  for (int half = 0; half < 2; ++half) {
    float y[32];
#pragma unroll
    for (int o = 0; o < 32; ++o) y[o] = b2[half * 32 + o];
#pragma unroll 4
    for (int vi = 0; vi < 64; ++vi) {
      float vv = v[vi];
#pragma unroll
      for (int o = 0; o < 32; ++o) y[o] = fmaf(w2[(half * 32 + o) * 64 + vi], vv, y[o]);
    }
#pragma unroll
    for (int o = 0; o < 32; ++o) {
      size_t i = (size_t)(half * 32 + o) * HW + p;
      uio[i] += gelu_f(y[o]);
    }
  }
}

// decoder: out[o,p] = sum_c w[o*64+c]*ua[c,p] + b[o]  (FLOAT32 output)
__global__ __launch_bounds__(256) void kdecf(const float* __restrict__ ua, const float* __restrict__ w,
                                             const float* __restrict__ b, float* __restrict__ out) {
  int p = blockIdx.x * 256 + threadIdx.x;
  float a0 = b[0], a1 = b[1];
  for (int c = 0; c < 64; ++c) {
    float xv = ua[(size_t)c * 262144 + p];
    a0 = fmaf(w[c], xv, a0);
    a1 = fmaf(w[64 + c], xv, a1);
  }
  out[p] = a0;
  out[262144 + p] = a1;
}

__global__ __launch_bounds__(256) void kcopyf(const float* __restrict__ src,
                                              float* __restrict__ out) {
  int p = blockIdx.x * 256 + threadIdx.x;
  out[p] = src[p];
}

extern "C" void kernel_launch(void* const* d_in, const int* in_sizes, int n_in,
                              void* d_out, int out_size, void* d_ws, size_t ws_size,
                              hipStream_t stream) {
  (void)in_sizes; (void)n_in; (void)out_size;
  const float* u_a = (const float*)d_in[0];
  const float* x_a = (const float*)d_in[1];
  const float* u_b = (const float*)d_in[2];
  const float* x_b = (const float*)d_in[3];
  const float* enc_a_w = (const float*)d_in[4];
  const float* enc_a_b = (const float*)d_in[5];
  const float* enc_b_w = (const float*)d_in[6];
  const float* enc_b_b = (const float*)d_in[7];
  const float* dec_w = (const float*)d_in[8];
  const float* dec_b = (const float*)d_in[9];
  const float* c1a_w = (const float*)d_in[10];
  const float* c1a_b = (const float*)d_in[11];
  const float* c2a_w = (const float*)d_in[12];
  const float* c2a_b = (const float*)d_in[13];
  const float* c1b_w = (const float*)d_in[14];
  const float* c1b_b = (const float*)d_in[15];
  const float* c2b_w = (const float*)d_in[16];
  const float* c2b_b = (const float*)d_in[17];
  const float* A_re = (const float*)d_in[18];
  const float* A_im = (const float*)d_in[19];

  if (ws_size < (size_t)38798336 * 4) return;

  float* F = (float*)d_ws;
  float* ua = F;
  float* ua_ = F + 16777216;
  float* ub = F + 33554432;
  float* ub_ = F + 34603008;
  float2* GTa = (float2*)(F + 35651584);
  float2* GTb = (float2*)(F + 37748736);
  float2* coef = (float2*)(F + 38273024);
  float2* coef2 = (float2*)(F + 38535168);
  float2* t512 = (float2*)(F + 38797312);
  float* out = (float*)d_out;  // FLOAT32 output buffer

  ktab<<<2, 256, 0, stream>>>(t512);

  const float FA = 1.f / 262144.f, FB = 1.f / 16384.f;
  kenc<262144><<<1024, 256, 0, stream>>>(x_a, u_a, enc_a_w, enc_a_b, ua);
  kenc<16384><<<64, 256, 0, stream>>>(x_b, u_b, enc_b_w, enc_b_b, ub);
  for (int l = 0; l < 4; ++l) {
    kfwd1<512, 9, 1><<<4096, 256, 0, stream>>>(ua, GTa, t512, FA);
    kfwd2<512, 1><<<256, 256, 0, stream>>>(GTa, coef, t512, 0);
    kfwd1<128, 7, 4><<<1024, 256, 0, stream>>>(ub, GTb, t512, FB);
    kfwd2<128, 4><<<256, 256, 0, stream>>>(GTb, coef, t512, 64);
    kmix<<<512, 256, 0, stream>>>(A_re + (size_t)l * 16777216, A_im + (size_t)l * 16777216,
                                  coef, coef2);
    kinv1<512, 9, 1><<<4096, 256, 0, stream>>>(coef2, GTa, t512, 0);
    kinv2<512, 9, 1><<<65536, 256, 0, stream>>>(GTa, ua_, t512);
    kconv<262144><<<1024, 256, 0, stream>>>(ua_, ua, c1a_w + l * 4096, c1a_b + l * 64,
                                            c2a_w + l * 4096, c2a_b + l * 64);
    if (l < 3) {
      kinv1<128, 7, 4><<<1024, 256, 0, stream>>>(coef2, GTb, t512, 64);
      kinv2<128, 7, 4><<<4096, 256, 0, stream>>>(GTb, ub_, t512);
      kconv<16384><<<64, 256, 0, stream>>>(ub_, ub, c1b_w + l * 4096, c1b_b + l * 64,
                                           c2b_w + l * 4096, c2b_b + l * 64);
    }
  }

  // FLOAT32 outputs in reference return order: [dec(ua) (2,512,512); ub (64,128,128)]
  kdecf<<<1024, 256, 0, stream>>>(ua, dec_w, dec_b, out);
  kcopyf<<<4096, 256, 0, stream>>>(ub, out + 524288);
}

// Round 19
// 1946.887 us; speedup vs baseline: 2.6999x; 2.6999x over previous
//
#include <hip/hip_runtime.h>
#include <hip/hip_bf16.h>
#include <math.h>

// Workspace (f32):
//  ua 0 / ua_ 16777216 / ub 33554432 / ub_ 34603008 / GTa 35651584
//  GTb 37748736 / coef 38273024 / coef2 38535168 / t512 38797312 ; end 38798336

__device__ __forceinline__ float gelu_f(float x) {
  float t = tanhf(0.7978845608028654f * (x + 0.044715f * x * x * x));
  return 0.5f * x * (1.0f + t);
}

__device__ __forceinline__ float2 cmulf(float2 a, float2 b) {
  return make_float2(a.x * b.x - a.y * b.y, a.x * b.y + a.y * b.x);
}

__global__ void ktab(float2* __restrict__ t512) {
  int k = blockIdx.x * 256 + threadIdx.x;
  if (k < 512) {
    float a = (float)((double)k * (6.283185307179586 / 512.0));
    t512[k] = make_float2(cosf(a), sinf(a));
  }
}

template <int HW>
__global__ __launch_bounds__(256) void kenc(const float* __restrict__ xin,
                                            const float* __restrict__ uin,
                                            const float* __restrict__ w,
                                            const float* __restrict__ b,
                                            float* __restrict__ out) {
  int p = blockIdx.x * 256 + threadIdx.x;
  float i0 = xin[p], i1 = xin[HW + p];
  float i2 = uin[p], i3 = uin[HW + p];
  for (int c = 0; c < 64; ++c)
    out[(size_t)c * HW + p] =
        w[c * 4 + 0] * i0 + w[c * 4 + 1] * i1 + w[c * 4 + 2] * i2 + w[c * 4 + 3] * i3 + b[c];
}

// fwd DFT stage1 (along w), LDS-staged rows + incremental rotation.
// block = c*(H/8)+h8; thread: kc=t>>3, hl=t&7.
template <int H, int MUL>
__global__ __launch_bounds__(256) void kfwd1(const float* __restrict__ x, float2* __restrict__ G,
                                             const float2* __restrict__ tw, float fs) {
  constexpr int PAD = H + 8;
  __shared__ float sm[8 * PAD];
  int blk = blockIdx.x;
  int c = blk / (H / 8);
  int h8 = blk % (H / 8);
  const float* src = x + ((size_t)c * H + h8 * 8) * H;
  for (int i = threadIdx.x; i < 2 * H; i += 256) {
    float4 g = ((const float4*)src)[i];
    int r = (i * 4) >> (H == 512 ? 9 : 7);
    int col = (i * 4) & (H - 1);
    *(float4*)&sm[r * PAD + col] = g;
  }
  __syncthreads();
  int kc = threadIdx.x >> 3;
  int hl = threadIdx.x & 7;
  float2 step = tw[(kc * MUL) & 511];
  float2 cur = make_float2(1.f, 0.f);
  float re = 0.f, im = 0.f;
  const float* row = sm + hl * PAD;
  for (int w = 0; w < H; ++w) {
    float xv = row[w];
    re = fmaf(xv, cur.x, re);
    im = fmaf(-xv, cur.y, im);
    cur = cmulf(cur, step);
  }
  int h = h8 * 8 + hl;
  G[((size_t)c * 32 + kc) * H + h] = make_float2(re * fs, im * fs);
}

// fwd DFT stage2 (along h): block per (c,kc); 8-lane partial sums + shuffle reduce.
template <int H, int MUL>
__global__ __launch_bounds__(256) void kfwd2(const float2* __restrict__ G, float2* __restrict__ coeff,
                                             const float2* __restrict__ tw, int cbase) {
  __shared__ float2 gs[H];
  int blk = blockIdx.x;
  int c = blk >> 5, kc = blk & 31;
  const float2* gr = G + ((size_t)c * 32 + kc) * H;
  for (int i = threadIdx.x; i < H; i += 256) gs[i] = gr[i];
  __syncthreads();
  int jr = threadIdx.x >> 3, sub = threadIdx.x & 7;
  int f = jr - 16;
  float2 cur = tw[(f * sub * MUL) & 511];
  float2 step = tw[(f * 8 * MUL) & 511];
  float re = 0.f, im = 0.f;
  for (int j = 0; j < H / 8; ++j) {
    float2 g = gs[sub + 8 * j];
    re += g.x * cur.x + g.y * cur.y;
    im += g.y * cur.x - g.x * cur.y;
    cur = cmulf(cur, step);
  }
  for (int d = 1; d < 8; d <<= 1) {
    re += __shfl_down(re, d, 8);
    im += __shfl_down(im, d, 8);
  }
  if (sub == 0) coeff[(size_t)(cbase + c) * 1024 + jr * 32 + kc] = make_float2(re, im);
}

__global__ __launch_bounds__(256) void kmix(const float* __restrict__ Are,
                                            const float* __restrict__ Aim,
                                            const float2* __restrict__ cin,
                                            float2* __restrict__ cout) {
  int idx = blockIdx.x * 256 + threadIdx.x;
  int mn = idx & 1023;
  int o = idx >> 10;
  const float* ar = Are + (size_t)o * 131072 + mn;
  const float* ai = Aim + (size_t)o * 131072 + mn;
  float re = 0.f, im = 0.f;
  for (int i = 0; i < 128; ++i) {
    float wr = ar[(size_t)i * 1024];
    float wi = ai[(size_t)i * 1024];
    float2 x = cin[(size_t)i * 1024 + mn];
    re += wr * x.x - wi * x.y;
    im += wr * x.y + wi * x.x;
  }
  cout[(size_t)o * 1024 + mn] = make_float2(re, im);
}

// inverse stage1 (along jr): block = c*(H/8)+h8; LDS-staged coeff[c]; rotation.
template <int H, int MUL>
__global__ __launch_bounds__(256) void kinv1(const float2* __restrict__ coeff, float2* __restrict__ T,
                                             const float2* __restrict__ tw, int cbase) {
  __shared__ float2 cs[1024];
  int blk = blockIdx.x;
  int c = blk / (H / 8);
  int h8 = blk % (H / 8);
  const float2* cr = coeff + (size_t)(cbase + c) * 1024;
  for (int i = threadIdx.x; i < 1024; i += 256) cs[i] = cr[i];
  __syncthreads();
  int kc = threadIdx.x & 31;
  int hl = threadIdx.x >> 5;
  int h = h8 * 8 + hl;
  float2 cur = tw[((-16) * h * MUL) & 511];
  float2 step = tw[(h * MUL) & 511];
  float re = 0.f, im = 0.f;
  for (int jr = 0; jr < 32; ++jr) {
    float2 x = cs[jr * 32 + kc];
    re += x.x * cur.x - x.y * cur.y;
    im += x.x * cur.y + x.y * cur.x;
    cur = cmulf(cur, step);
  }
  float wgt = (kc == 0) ? 1.f : 2.f;
  T[((size_t)c * H + h) * 32 + kc] = make_float2(re * wgt, im * wgt);
}

// inverse stage2 (c2r along w): LDS-staged T rows + rotation; coalesced writes.
// RPB=1 (H=512): block per row, 2 outputs/thread. RPB=2 (H=128): 2 rows/block.
template <int H, int MUL, int RPB>
__global__ __launch_bounds__(256) void kinv2(const float2* __restrict__ T, float* __restrict__ out,
                                             const float2* __restrict__ tw) {
  __shared__ float2 ts[RPB * 32];
  size_t row0 = (size_t)blockIdx.x * RPB;
  for (int i = threadIdx.x; i < RPB * 32; i += 256) ts[i] = T[row0 * 32 + i];
  __syncthreads();
  if (RPB == 1) {
    int w0 = threadIdx.x;
    float2 b0 = tw[(w0 * MUL) & 511];
    float2 b1 = tw[((w0 + 256) * MUL) & 511];
    float2 c0 = make_float2(1.f, 0.f), c1 = make_float2(1.f, 0.f);
    float a0 = 0.f, a1 = 0.f;
    for (int kc = 0; kc < 32; ++kc) {
      float2 t = ts[kc];
      a0 += t.x * c0.x - t.y * c0.y;
      a1 += t.x * c1.x - t.y * c1.y;
      c0 = cmulf(c0, b0);
      c1 = cmulf(c1, b1);
    }
    out[row0 * H + w0] = a0;
    out[row0 * H + w0 + 256] = a1;
  } else {
    int r = threadIdx.x >> 7;
    int w0 = threadIdx.x & 127;
    float2 b0 = tw[(w0 * MUL) & 511];
    float2 c0 = make_float2(1.f, 0.f);
    float a0 = 0.f;
    for (int kc = 0; kc < 32; ++kc) {
      float2 t = ts[r * 32 + kc];
      a0 += t.x * c0.x - t.y * c0.y;
      c0 = cmulf(c0, b0);
    }
    out[(row0 + r) * H + w0] = a0;
  }
}

template <int HW>
__global__ __launch_bounds__(256) void kconv(const float* __restrict__ xin, float* __restrict__ uio,
                                             const float* __restrict__ w1, const float* __restrict__ b1,
                                             const float* __restrict__ w2, const float* __restrict__ b2) {
  int p = blockIdx.x * 256 + threadIdx.x;
  float v[64];
#pragma unroll
  for (int o = 0; o < 64; ++o) v[o] = b1[o];
  for (int ci = 0; ci < 64; ++ci) {
    float xv = xin[(size_t)ci * HW + p];
#pragma unroll
    for (int o = 0; o < 64; ++o) v[o] = fmaf(w1[o * 64 + ci], xv, v[o]);
  }
#pragma unroll
  for (int o = 0; o < 64; ++o) v[o] = gelu_f(v[o]);
  for (int half = 0; half < 2; ++half) {
    float y[32];
#pragma unroll
    for (int o = 0; o < 32; ++o) y[o] = b2[half * 32 + o];
#pragma unroll 4
    for (int vi = 0; vi < 64; ++vi) {
      float vv = v[vi];
#pragma unroll
      for (int o = 0; o < 32; ++o) y[o] = fmaf(w2[(half * 32 + o) * 64 + vi], vv, y[o]);
    }
#pragma unroll
    for (int o = 0; o < 32; ++o) {
      size_t i = (size_t)(half * 32 + o) * HW + p;
      uio[i] += gelu_f(y[o]);
    }
  }
}

__global__ __launch_bounds__(256) void kdecf(const float* __restrict__ ua, const float* __restrict__ w,
                                             const float* __restrict__ b, float* __restrict__ out) {
  int p = blockIdx.x * 256 + threadIdx.x;
  float a0 = b[0], a1 = b[1];
  for (int c = 0; c < 64; ++c) {
    float xv = ua[(size_t)c * 262144 + p];
    a0 = fmaf(w[c], xv, a0);
    a1 = fmaf(w[64 + c], xv, a1);
  }
  out[p] = a0;
  out[262144 + p] = a1;
}

__global__ __launch_bounds__(256) void kcopyf(const float* __restrict__ src, float* __restrict__ out) {
  int p = blockIdx.x * 256 + threadIdx.x;
  out[p] = src[p];
}

extern "C" void kernel_launch(void* const* d_in, const int* in_sizes, int n_in,
                              void* d_out, int out_size, void* d_ws, size_t ws_size,
                              hipStream_t stream) {
  (void)in_sizes; (void)n_in; (void)out_size;
  const float* u_a = (const float*)d_in[0];
  const float* x_a = (const float*)d_in[1];
  const float* u_b = (const float*)d_in[2];
  const float* x_b = (const float*)d_in[3];
  const float* enc_a_w = (const float*)d_in[4];
  const float* enc_a_b = (const float*)d_in[5];
  const float* enc_b_w = (const float*)d_in[6];
  const float* enc_b_b = (const float*)d_in[7];
  const float* dec_w = (const float*)d_in[8];
  const float* dec_b = (const float*)d_in[9];
  const float* c1a_w = (const float*)d_in[10];
  const float* c1a_b = (const float*)d_in[11];
  const float* c2a_w = (const float*)d_in[12];
  const float* c2a_b = (const float*)d_in[13];
  const float* c1b_w = (const float*)d_in[14];
  const float* c1b_b = (const float*)d_in[15];
  const float* c2b_w = (const float*)d_in[16];
  const float* c2b_b = (const float*)d_in[17];
  const float* A_re = (const float*)d_in[18];
  const float* A_im = (const float*)d_in[19];

  if (ws_size < (size_t)38798336 * 4) return;

  float* F = (float*)d_ws;
  float* ua = F;
  float* ua_ = F + 16777216;
  float* ub = F + 33554432;
  float* ub_ = F + 34603008;
  float2* GTa = (float2*)(F + 35651584);
  float2* GTb = (float2*)(F + 37748736);
  float2* coef = (float2*)(F + 38273024);
  float2* coef2 = (float2*)(F + 38535168);
  float2* t512 = (float2*)(F + 38797312);
  float* out = (float*)d_out;

  ktab<<<2, 256, 0, stream>>>(t512);

  const float FA = 1.f / 262144.f, FB = 1.f / 16384.f;
  kenc<262144><<<1024, 256, 0, stream>>>(x_a, u_a, enc_a_w, enc_a_b, ua);
  kenc<16384><<<64, 256, 0, stream>>>(x_b, u_b, enc_b_w, enc_b_b, ub);
  for (int l = 0; l < 4; ++l) {
    kfwd1<512, 1><<<4096, 256, 0, stream>>>(ua, GTa, t512, FA);
    kfwd2<512, 1><<<2048, 256, 0, stream>>>(GTa, coef, t512, 0);
    kfwd1<128, 4><<<1024, 256, 0, stream>>>(ub, GTb, t512, FB);
    kfwd2<128, 4><<<2048, 256, 0, stream>>>(GTb, coef, t512, 64);
    kmix<<<512, 256, 0, stream>>>(A_re + (size_t)l * 16777216, A_im + (size_t)l * 16777216,
                                  coef, coef2);
    kinv1<512, 1><<<4096, 256, 0, stream>>>(coef2, GTa, t512, 0);
    kinv2<512, 1, 1><<<32768, 256, 0, stream>>>(GTa, ua_, t512);
    kconv<262144><<<1024, 256, 0, stream>>>(ua_, ua, c1a_w + l * 4096, c1a_b + l * 64,
                                            c2a_w + l * 4096, c2a_b + l * 64);
    if (l < 3) {
      kinv1<128, 4><<<1024, 256, 0, stream>>>(coef2, GTb, t512, 64);
      kinv2<128, 4, 2><<<4096, 256, 0, stream>>>(GTb, ub_, t512);
      kconv<16384><<<64, 256, 0, stream>>>(ub_, ub, c1b_w + l * 4096, c1b_b + l * 64,
                                           c2b_w + l * 4096, c2b_b + l * 64);
    }
  }

  // FLOAT32 outputs, reference order: [dec(ua) (2,512,512); ub (64,128,128)]
  kdecf<<<1024, 256, 0, stream>>>(ua, dec_w, dec_b, out);
  kcopyf<<<4096, 256, 0, stream>>>(ub, out + 524288);
}

// Round 20
// 1436.523 us; speedup vs baseline: 3.6592x; 1.3553x over previous
//
#include <hip/hip_runtime.h>
#include <hip/hip_bf16.h>
#include <math.h>

// Workspace (f32):
//  ua 0 / ua_ 16777216 / ub 33554432 / ub_ 34603008 / GTa 35651584
//  GTb 37748736 / coef 38273024 / coef2 38535168 / t512 38797312 ; end 38798336

__device__ __forceinline__ float gelu_f(float x) {
  float t = tanhf(0.7978845608028654f * (x + 0.044715f * x * x * x));
  return 0.5f * x * (1.0f + t);
}

__device__ __forceinline__ float2 cmulf(float2 a, float2 b) {
  return make_float2(a.x * b.x - a.y * b.y, a.x * b.y + a.y * b.x);
}

__global__ void ktab(float2* __restrict__ t512) {
  int k = blockIdx.x * 256 + threadIdx.x;
  if (k < 512) {
    float a = (float)((double)k * (6.283185307179586 / 512.0));
    t512[k] = make_float2(cosf(a), sinf(a));
  }
}

template <int HW>
__global__ __launch_bounds__(256) void kenc(const float* __restrict__ xin,
                                            const float* __restrict__ uin,
                                            const float* __restrict__ w,
                                            const float* __restrict__ b,
                                            float* __restrict__ out) {
  int p = blockIdx.x * 256 + threadIdx.x;
  float i0 = xin[p], i1 = xin[HW + p];
  float i2 = uin[p], i3 = uin[HW + p];
  for (int c = 0; c < 64; ++c)
    out[(size_t)c * HW + p] =
        w[c * 4 + 0] * i0 + w[c * 4 + 1] * i1 + w[c * 4 + 2] * i2 + w[c * 4 + 3] * i3 + b[c];
}

// fwd DFT stage1 (along w), LDS rows + incremental rotation.
template <int H, int MUL>
__global__ __launch_bounds__(256) void kfwd1(const float* __restrict__ x, float2* __restrict__ G,
                                             const float2* __restrict__ tw, float fs) {
  constexpr int PAD = H + 8;
  __shared__ float sm[8 * PAD];
  int blk = blockIdx.x;
  int c = blk / (H / 8);
  int h8 = blk % (H / 8);
  const float* src = x + ((size_t)c * H + h8 * 8) * H;
  for (int i = threadIdx.x; i < 2 * H; i += 256) {
    float4 g = ((const float4*)src)[i];
    int r = (i * 4) >> (H == 512 ? 9 : 7);
    int col = (i * 4) & (H - 1);
    *(float4*)&sm[r * PAD + col] = g;
  }
  __syncthreads();
  int kc = threadIdx.x >> 3;
  int hl = threadIdx.x & 7;
  float2 step = tw[(kc * MUL) & 511];
  float2 cur = make_float2(1.f, 0.f);
  float re = 0.f, im = 0.f;
  const float* row = sm + hl * PAD;
  for (int w = 0; w < H; ++w) {
    float xv = row[w];
    re = fmaf(xv, cur.x, re);
    im = fmaf(-xv, cur.y, im);
    cur = cmulf(cur, step);
  }
  int h = h8 * 8 + hl;
  G[((size_t)c * 32 + kc) * H + h] = make_float2(re * fs, im * fs);
}

// fwd DFT stage2 (along h)
template <int H, int MUL>
__global__ __launch_bounds__(256) void kfwd2(const float2* __restrict__ G, float2* __restrict__ coeff,
                                             const float2* __restrict__ tw, int cbase) {
  __shared__ float2 gs[H];
  int blk = blockIdx.x;
  int c = blk >> 5, kc = blk & 31;
  const float2* gr = G + ((size_t)c * 32 + kc) * H;
  for (int i = threadIdx.x; i < H; i += 256) gs[i] = gr[i];
  __syncthreads();
  int jr = threadIdx.x >> 3, sub = threadIdx.x & 7;
  int f = jr - 16;
  float2 cur = tw[(f * sub * MUL) & 511];
  float2 step = tw[(f * 8 * MUL) & 511];
  float re = 0.f, im = 0.f;
  for (int j = 0; j < H / 8; ++j) {
    float2 g = gs[sub + 8 * j];
    re += g.x * cur.x + g.y * cur.y;
    im += g.y * cur.x - g.x * cur.y;
    cur = cmulf(cur, step);
  }
  for (int d = 1; d < 8; d <<= 1) {
    re += __shfl_down(re, d, 8);
    im += __shfl_down(im, d, 8);
  }
  if (sub == 0) coeff[(size_t)(cbase + c) * 1024 + jr * 32 + kc] = make_float2(re, im);
}

__global__ __launch_bounds__(256) void kmix(const float* __restrict__ Are,
                                            const float* __restrict__ Aim,
                                            const float2* __restrict__ cin,
                                            float2* __restrict__ cout) {
  int idx = blockIdx.x * 256 + threadIdx.x;
  int mn = idx & 1023;
  int o = idx >> 10;
  const float* ar = Are + (size_t)o * 131072 + mn;
  const float* ai = Aim + (size_t)o * 131072 + mn;
  float re = 0.f, im = 0.f;
  for (int i = 0; i < 128; ++i) {
    float wr = ar[(size_t)i * 1024];
    float wi = ai[(size_t)i * 1024];
    float2 x = cin[(size_t)i * 1024 + mn];
    re += wr * x.x - wi * x.y;
    im += wr * x.y + wi * x.x;
  }
  cout[(size_t)o * 1024 + mn] = make_float2(re, im);
}

// inverse stage1 (along jr)
template <int H, int MUL>
__global__ __launch_bounds__(256) void kinv1(const float2* __restrict__ coeff, float2* __restrict__ T,
                                             const float2* __restrict__ tw, int cbase) {
  __shared__ float2 cs[1024];
  int blk = blockIdx.x;
  int c = blk / (H / 8);
  int h8 = blk % (H / 8);
  const float2* cr = coeff + (size_t)(cbase + c) * 1024;
  for (int i = threadIdx.x; i < 1024; i += 256) cs[i] = cr[i];
  __syncthreads();
  int kc = threadIdx.x & 31;
  int hl = threadIdx.x >> 5;
  int h = h8 * 8 + hl;
  float2 cur = tw[((-16) * h * MUL) & 511];
  float2 step = tw[(h * MUL) & 511];
  float re = 0.f, im = 0.f;
  for (int jr = 0; jr < 32; ++jr) {
    float2 x = cs[jr * 32 + kc];
    re += x.x * cur.x - x.y * cur.y;
    im += x.x * cur.y + x.y * cur.x;
    cur = cmulf(cur, step);
  }
  float wgt = (kc == 0) ? 1.f : 2.f;
  T[((size_t)c * H + h) * 32 + kc] = make_float2(re * wgt, im * wgt);
}

// inverse stage2 (c2r along w)
template <int H, int MUL, int RPB>
__global__ __launch_bounds__(256) void kinv2(const float2* __restrict__ T, float* __restrict__ out,
                                             const float2* __restrict__ tw) {
  __shared__ float2 ts[RPB * 32];
  size_t row0 = (size_t)blockIdx.x * RPB;
  for (int i = threadIdx.x; i < RPB * 32; i += 256) ts[i] = T[row0 * 32 + i];
  __syncthreads();
  if (RPB == 1) {
    int w0 = threadIdx.x;
    float2 b0 = tw[(w0 * MUL) & 511];
    float2 b1 = tw[((w0 + 256) * MUL) & 511];
    float2 c0 = make_float2(1.f, 0.f), c1 = make_float2(1.f, 0.f);
    float a0 = 0.f, a1 = 0.f;
    for (int kc = 0; kc < 32; ++kc) {
      float2 t = ts[kc];
      a0 += t.x * c0.x - t.y * c0.y;
      a1 += t.x * c1.x - t.y * c1.y;
      c0 = cmulf(c0, b0);
      c1 = cmulf(c1, b1);
    }
    out[row0 * H + w0] = a0;
    out[row0 * H + w0 + 256] = a1;
  } else {
    int r = threadIdx.x >> 7;
    int w0 = threadIdx.x & 127;
    float2 b0 = tw[(w0 * MUL) & 511];
    float2 c0 = make_float2(1.f, 0.f);
    float a0 = 0.f;
    for (int kc = 0; kc < 32; ++kc) {
      float2 t = ts[r * 32 + kc];
      a0 += t.x * c0.x - t.y * c0.y;
      c0 = cmulf(c0, b0);
    }
    out[(row0 + r) * H + w0] = a0;
  }
}

// LDS-tiled residual MLP: uio[:,p] += gelu(W2*gelu(W1*x+b1)+b2), 64 pixels/block.
// Thread computes 4 out-ch x 4 pixels; W/X/H staged in padded LDS (no spills).
template <int HW>
__global__ __launch_bounds__(256) void kconv(const float* __restrict__ xin, float* __restrict__ uio,
                                             const float* __restrict__ w1, const float* __restrict__ b1,
                                             const float* __restrict__ w2, const float* __restrict__ b2) {
  __shared__ float Xs[64][65];
  __shared__ float Hs[64][65];
  __shared__ float Ws[64][65];
  int p0 = blockIdx.x * 64;
  int t = threadIdx.x;
  // stage X and W1
  for (int i = t; i < 4096; i += 256) {
    int r = i >> 6, cidx = i & 63;
    Xs[r][cidx] = xin[(size_t)r * HW + p0 + cidx];
    Ws[r][cidx] = w1[i];
  }
  __syncthreads();
  int ocb = (t >> 4) * 4;   // 4 out channels
  int pb = (t & 15) * 4;    // 4 pixels
  float acc[16];
  {
#pragma unroll
    for (int i = 0; i < 4; ++i) {
      float bi = b1[ocb + i];
#pragma unroll
      for (int j = 0; j < 4; ++j) acc[i * 4 + j] = bi;
    }
    for (int ci = 0; ci < 64; ++ci) {
      float a0 = Ws[ocb + 0][ci], a1 = Ws[ocb + 1][ci], a2 = Ws[ocb + 2][ci], a3 = Ws[ocb + 3][ci];
      float x0 = Xs[ci][pb + 0], x1 = Xs[ci][pb + 1], x2 = Xs[ci][pb + 2], x3 = Xs[ci][pb + 3];
      acc[0] = fmaf(a0, x0, acc[0]); acc[1] = fmaf(a0, x1, acc[1]);
      acc[2] = fmaf(a0, x2, acc[2]); acc[3] = fmaf(a0, x3, acc[3]);
      acc[4] = fmaf(a1, x0, acc[4]); acc[5] = fmaf(a1, x1, acc[5]);
      acc[6] = fmaf(a1, x2, acc[6]); acc[7] = fmaf(a1, x3, acc[7]);
      acc[8] = fmaf(a2, x0, acc[8]); acc[9] = fmaf(a2, x1, acc[9]);
      acc[10] = fmaf(a2, x2, acc[10]); acc[11] = fmaf(a2, x3, acc[11]);
      acc[12] = fmaf(a3, x0, acc[12]); acc[13] = fmaf(a3, x1, acc[13]);
      acc[14] = fmaf(a3, x2, acc[14]); acc[15] = fmaf(a3, x3, acc[15]);
    }
#pragma unroll
    for (int i = 0; i < 4; ++i)
#pragma unroll
      for (int j = 0; j < 4; ++j) Hs[ocb + i][pb + j] = gelu_f(acc[i * 4 + j]);
  }
  __syncthreads();
  // stage W2 (overwrites Ws)
  for (int i = t; i < 4096; i += 256) Ws[i >> 6][i & 63] = w2[i];
  __syncthreads();
  {
#pragma unroll
    for (int i = 0; i < 4; ++i) {
      float bi = b2[ocb + i];
#pragma unroll
      for (int j = 0; j < 4; ++j) acc[i * 4 + j] = bi;
    }
    for (int ci = 0; ci < 64; ++ci) {
      float a0 = Ws[ocb + 0][ci], a1 = Ws[ocb + 1][ci], a2 = Ws[ocb + 2][ci], a3 = Ws[ocb + 3][ci];
      float x0 = Hs[ci][pb + 0], x1 = Hs[ci][pb + 1], x2 = Hs[ci][pb + 2], x3 = Hs[ci][pb + 3];
      acc[0] = fmaf(a0, x0, acc[0]); acc[1] = fmaf(a0, x1, acc[1]);
      acc[2] = fmaf(a0, x2, acc[2]); acc[3] = fmaf(a0, x3, acc[3]);
      acc[4] = fmaf(a1, x0, acc[4]); acc[5] = fmaf(a1, x1, acc[5]);
      acc[6] = fmaf(a1, x2, acc[6]); acc[7] = fmaf(a1, x3, acc[7]);
      acc[8] = fmaf(a2, x0, acc[8]); acc[9] = fmaf(a2, x1, acc[9]);
      acc[10] = fmaf(a2, x2, acc[10]); acc[11] = fmaf(a2, x3, acc[11]);
      acc[12] = fmaf(a3, x0, acc[12]); acc[13] = fmaf(a3, x1, acc[13]);
      acc[14] = fmaf(a3, x2, acc[14]); acc[15] = fmaf(a3, x3, acc[15]);
    }
#pragma unroll
    for (int i = 0; i < 4; ++i) {
      float4* dst = (float4*)&uio[(size_t)(ocb + i) * HW + p0 + pb];
      float4 u = *dst;
      u.x += gelu_f(acc[i * 4 + 0]);
      u.y += gelu_f(acc[i * 4 + 1]);
      u.z += gelu_f(acc[i * 4 + 2]);
      u.w += gelu_f(acc[i * 4 + 3]);
      *dst = u;
    }
  }
}

__global__ __launch_bounds__(256) void kdecf(const float* __restrict__ ua, const float* __restrict__ w,
                                             const float* __restrict__ b, float* __restrict__ out) {
  int p = blockIdx.x * 256 + threadIdx.x;
  float a0 = b[0], a1 = b[1];
  for (int c = 0; c < 64; ++c) {
    float xv = ua[(size_t)c * 262144 + p];
    a0 = fmaf(w[c], xv, a0);
    a1 = fmaf(w[64 + c], xv, a1);
  }
  out[p] = a0;
  out[262144 + p] = a1;
}

__global__ __launch_bounds__(256) void kcopyf(const float* __restrict__ src, float* __restrict__ out) {
  int p = blockIdx.x * 256 + threadIdx.x;
  out[p] = src[p];
}

extern "C" void kernel_launch(void* const* d_in, const int* in_sizes, int n_in,
                              void* d_out, int out_size, void* d_ws, size_t ws_size,
                              hipStream_t stream) {
  (void)in_sizes; (void)n_in; (void)out_size;
  const float* u_a = (const float*)d_in[0];
  const float* x_a = (const float*)d_in[1];
  const float* u_b = (const float*)d_in[2];
  const float* x_b = (const float*)d_in[3];
  const float* enc_a_w = (const float*)d_in[4];
  const float* enc_a_b = (const float*)d_in[5];
  const float* enc_b_w = (const float*)d_in[6];
  const float* enc_b_b = (const float*)d_in[7];
  const float* dec_w = (const float*)d_in[8];
  const float* dec_b = (const float*)d_in[9];
  const float* c1a_w = (const float*)d_in[10];
  const float* c1a_b = (const float*)d_in[11];
  const float* c2a_w = (const float*)d_in[12];
  const float* c2a_b = (const float*)d_in[13];
  const float* c1b_w = (const float*)d_in[14];
  const float* c1b_b = (const float*)d_in[15];
  const float* c2b_w = (const float*)d_in[16];
  const float* c2b_b = (const float*)d_in[17];
  const float* A_re = (const float*)d_in[18];
  const float* A_im = (const float*)d_in[19];

  if (ws_size < (size_t)38798336 * 4) return;

  float* F = (float*)d_ws;
  float* ua = F;
  float* ua_ = F + 16777216;
  float* ub = F + 33554432;
  float* ub_ = F + 34603008;
  float2* GTa = (float2*)(F + 35651584);
  float2* GTb = (float2*)(F + 37748736);
  float2* coef = (float2*)(F + 38273024);
  float2* coef2 = (float2*)(F + 38535168);
  float2* t512 = (float2*)(F + 38797312);
  float* out = (float*)d_out;

  ktab<<<2, 256, 0, stream>>>(t512);

  const float FA = 1.f / 262144.f, FB = 1.f / 16384.f;
  kenc<262144><<<1024, 256, 0, stream>>>(x_a, u_a, enc_a_w, enc_a_b, ua);
  kenc<16384><<<64, 256, 0, stream>>>(x_b, u_b, enc_b_w, enc_b_b, ub);
  for (int l = 0; l < 4; ++l) {
    kfwd1<512, 1><<<4096, 256, 0, stream>>>(ua, GTa, t512, FA);
    kfwd2<512, 1><<<2048, 256, 0, stream>>>(GTa, coef, t512, 0);
    kfwd1<128, 4><<<1024, 256, 0, stream>>>(ub, GTb, t512, FB);
    kfwd2<128, 4><<<2048, 256, 0, stream>>>(GTb, coef, t512, 64);
    kmix<<<512, 256, 0, stream>>>(A_re + (size_t)l * 16777216, A_im + (size_t)l * 16777216,
                                  coef, coef2);
    kinv1<512, 1><<<4096, 256, 0, stream>>>(coef2, GTa, t512, 0);
    kinv2<512, 1, 1><<<32768, 256, 0, stream>>>(GTa, ua_, t512);
    kconv<262144><<<4096, 256, 0, stream>>>(ua_, ua, c1a_w + l * 4096, c1a_b + l * 64,
                                            c2a_w + l * 4096, c2a_b + l * 64);
    if (l < 3) {
      kinv1<128, 4><<<1024, 256, 0, stream>>>(coef2, GTb, t512, 64);
      kinv2<128, 4, 2><<<4096, 256, 0, stream>>>(GTb, ub_, t512);
      kconv<16384><<<256, 256, 0, stream>>>(ub_, ub, c1b_w + l * 4096, c1b_b + l * 64,
                                            c2b_w + l * 4096, c2b_b + l * 64);
    }
  }

  // FLOAT32 outputs, reference order: [dec(ua) (2,512,512); ub (64,128,128)]
  kdecf<<<1024, 256, 0, stream>>>(ua, dec_w, dec_b, out);
  kcopyf<<<4096, 256, 0, stream>>>(ub, out + 524288);
}

// Round 21
// 991.909 us; speedup vs baseline: 5.2993x; 1.4482x over previous
//
#include <hip/hip_runtime.h>
#include <hip/hip_bf16.h>
#include <math.h>

// Workspace (f32):
//  ua 0 / ua_ 16777216 / ub 33554432 / ub_ 34603008 / GTa 35651584
//  GTb 37748736 / coef 38273024 / coef2 38535168 / t512 38797312 ; end 38798336

__device__ __forceinline__ float gelu_f(float x) {
  float t = tanhf(0.7978845608028654f * (x + 0.044715f * x * x * x));
  return 0.5f * x * (1.0f + t);
}

__device__ __forceinline__ float2 cmulf(float2 a, float2 b) {
  return make_float2(a.x * b.x - a.y * b.y, a.x * b.y + a.y * b.x);
}

__global__ void ktab(float2* __restrict__ t512) {
  int k = blockIdx.x * 256 + threadIdx.x;
  if (k < 512) {
    float a = (float)((double)k * (6.283185307179586 / 512.0));
    t512[k] = make_float2(cosf(a), sinf(a));
  }
}

template <int HW>
__global__ __launch_bounds__(256) void kenc(const float* __restrict__ xin,
                                            const float* __restrict__ uin,
                                            const float* __restrict__ w,
                                            const float* __restrict__ b,
                                            float* __restrict__ out) {
  int p = blockIdx.x * 256 + threadIdx.x;
  float i0 = xin[p], i1 = xin[HW + p];
  float i2 = uin[p], i3 = uin[HW + p];
  for (int c = 0; c < 64; ++c)
    out[(size_t)c * HW + p] =
        w[c * 4 + 0] * i0 + w[c * 4 + 1] * i1 + w[c * 4 + 2] * i2 + w[c * 4 + 3] * i3 + b[c];
}

// fwd DFT stage1 (along w) via Goertzel: X = e^{i0}v1 - v2 after v = x + 2cos*v1 - v2.
// block = c*(H/8)+h8; thread: kc=t>>3, hl=t&7 (keeps 64B-chunk G writes).
template <int H, int MUL>
__global__ __launch_bounds__(256) void kfwd1(const float* __restrict__ x, float2* __restrict__ G,
                                             const float2* __restrict__ tw, float fs) {
  constexpr int PAD = H + 8;
  __shared__ float sm[8 * PAD];
  int c = blockIdx.x / (H / 8);
  int h8 = blockIdx.x % (H / 8);
  const float* src = x + ((size_t)c * H + h8 * 8) * H;
  for (int i = threadIdx.x; i < 2 * H; i += 256) {
    float4 g = ((const float4*)src)[i];
    int r = (i * 4) >> (H == 512 ? 9 : 7);
    int col = (i * 4) & (H - 1);
    *(float4*)&sm[r * PAD + col] = g;
  }
  __syncthreads();
  int kc = threadIdx.x >> 3;
  int hl = threadIdx.x & 7;
  float2 w0 = tw[(kc * MUL) & 511];
  float twoc = 2.f * w0.x;
  const float* row = sm + hl * PAD;
  float v1 = 0.f, v2 = 0.f;
#pragma unroll 4
  for (int w = 0; w < H; w += 2) {
    v2 = fmaf(twoc, v1, row[w] - v2);
    v1 = fmaf(twoc, v2, row[w + 1] - v1);
  }
  int h = h8 * 8 + hl;
  G[((size_t)c * 32 + kc) * H + h] =
      make_float2(fs * fmaf(w0.x, v1, -v2), fs * (w0.y * v1));
}

// fwd DFT stage2 (along h): rotation + 8-lane shuffle reduce.
template <int H, int MUL>
__global__ __launch_bounds__(256) void kfwd2(const float2* __restrict__ G, float2* __restrict__ coeff,
                                             const float2* __restrict__ tw, int cbase) {
  __shared__ float2 gs[H];
  int c = blockIdx.x >> 5, kc = blockIdx.x & 31;
  const float2* gr = G + ((size_t)c * 32 + kc) * H;
  for (int i = threadIdx.x; i < H; i += 256) gs[i] = gr[i];
  __syncthreads();
  int jr = threadIdx.x >> 3, sub = threadIdx.x & 7;
  int f = jr - 16;
  float2 cur = tw[(f * sub * MUL) & 511];
  float2 step = tw[(f * 8 * MUL) & 511];
  float re = 0.f, im = 0.f;
  for (int j = 0; j < H / 8; ++j) {
    float2 g = gs[sub + 8 * j];
    re += g.x * cur.x + g.y * cur.y;
    im += g.y * cur.x - g.x * cur.y;
    cur = cmulf(cur, step);
  }
  for (int d = 1; d < 8; d <<= 1) {
    re += __shfl_down(re, d, 8);
    im += __shfl_down(im, d, 8);
  }
  if (sub == 0) coeff[(size_t)(cbase + c) * 1024 + jr * 32 + kc] = make_float2(re, im);
}

__global__ __launch_bounds__(256) void kmix(const float* __restrict__ Are,
                                            const float* __restrict__ Aim,
                                            const float2* __restrict__ cin,
                                            float2* __restrict__ cout) {
  int idx = blockIdx.x * 256 + threadIdx.x;
  int mn = idx & 1023;
  int o = idx >> 10;
  const float* ar = Are + (size_t)o * 131072 + mn;
  const float* ai = Aim + (size_t)o * 131072 + mn;
  float re = 0.f, im = 0.f;
  for (int i = 0; i < 128; ++i) {
    float wr = ar[(size_t)i * 1024];
    float wi = ai[(size_t)i * 1024];
    float2 x = cin[(size_t)i * 1024 + mn];
    re += wr * x.x - wi * x.y;
    im += wr * x.y + wi * x.x;
  }
  cout[(size_t)o * 1024 + mn] = make_float2(re, im);
}

// inverse stage1 (along jr): rotation; wgt folded here.
template <int H, int MUL>
__global__ __launch_bounds__(256) void kinv1(const float2* __restrict__ coeff, float2* __restrict__ T,
                                             const float2* __restrict__ tw, int cbase) {
  __shared__ float2 cs[1024];
  int c = blockIdx.x / (H / 8);
  int h8 = blockIdx.x % (H / 8);
  const float2* cr = coeff + (size_t)(cbase + c) * 1024;
  for (int i = threadIdx.x; i < 1024; i += 256) cs[i] = cr[i];
  __syncthreads();
  int kc = threadIdx.x & 31;
  int hl = threadIdx.x >> 5;
  int h = h8 * 8 + hl;
  float2 cur = tw[((-16) * h * MUL) & 511];
  float2 step = tw[(h * MUL) & 511];
  float re = 0.f, im = 0.f;
  for (int jr = 0; jr < 32; ++jr) {
    float2 x = cs[jr * 32 + kc];
    re += x.x * cur.x - x.y * cur.y;
    im += x.x * cur.y + x.y * cur.x;
    cur = cmulf(cur, step);
  }
  float wgt = (kc == 0) ? 1.f : 2.f;
  T[((size_t)c * H + h) * 32 + kc] = make_float2(re * wgt, im * wgt);
}

// inverse stage2 (c2r): 4 outputs/thread at stride H/4 sharing one rotator via i^{j*kc}.
// out[w0+j*H/4] = sum_kc Re(T_kc * c0(kc) * i^{j*kc}); kc unrolled by 4 => static signs.
template <int H, int MUL, int RPB>
__global__ __launch_bounds__(256) void kinv2(const float2* __restrict__ T, float* __restrict__ out,
                                             const float2* __restrict__ tw) {
  constexpr int QW = H / 4;
  __shared__ float2 ts[RPB * 32];
  size_t row0 = (size_t)blockIdx.x * RPB;
  for (int i = threadIdx.x; i < RPB * 32; i += 256) ts[i] = T[row0 * 32 + i];
  __syncthreads();
  int r = threadIdx.x / QW;
  int w0 = threadIdx.x % QW;
  float2 b = tw[(w0 * MUL) & 511];
  float2 c = make_float2(1.f, 0.f);
  float a0 = 0.f, a1 = 0.f, a2 = 0.f, a3 = 0.f;
  const float2* tr = &ts[r * 32];
#pragma unroll
  for (int kc = 0; kc < 32; kc += 4) {
    float2 t0 = tr[kc];
    float zre = t0.x * c.x - t0.y * c.y;
    a0 += zre; a1 += zre; a2 += zre; a3 += zre;
    c = cmulf(c, b);
    t0 = tr[kc + 1];
    zre = t0.x * c.x - t0.y * c.y;
    float zim = t0.x * c.y + t0.y * c.x;
    a0 += zre; a1 -= zim; a2 -= zre; a3 += zim;
    c = cmulf(c, b);
    t0 = tr[kc + 2];
    zre = t0.x * c.x - t0.y * c.y;
    a0 += zre; a1 -= zre; a2 += zre; a3 -= zre;
    c = cmulf(c, b);
    t0 = tr[kc + 3];
    zre = t0.x * c.x - t0.y * c.y;
    zim = t0.x * c.y + t0.y * c.x;
    a0 += zre; a1 += zim; a2 -= zre; a3 -= zim;
    c = cmulf(c, b);
  }
  float* orow = out + (row0 + r) * H + w0;
  orow[0] = a0;
  orow[QW] = a1;
  orow[2 * QW] = a2;
  orow[3 * QW] = a3;
}

// LDS-tiled residual MLP, 2 LDS arrays (h overwrites Xs): 64 px/block, 4oc x 4px tiles.
template <int HW>
__global__ __launch_bounds__(256) void kconv(const float* __restrict__ xin, float* __restrict__ uio,
                                             const float* __restrict__ w1, const float* __restrict__ b1,
                                             const float* __restrict__ w2, const float* __restrict__ b2) {
  __shared__ float Xs[64][65];
  __shared__ float Ws[64][65];
  int p0 = blockIdx.x * 64;
  int t = threadIdx.x;
  for (int i = t; i < 4096; i += 256) {
    int r = i >> 6, cidx = i & 63;
    Xs[r][cidx] = xin[(size_t)r * HW + p0 + cidx];
    Ws[r][cidx] = w1[i];
  }
  __syncthreads();
  int ocb = (t >> 4) * 4;
  int pb = (t & 15) * 4;
  float acc[16];
#pragma unroll
  for (int i = 0; i < 4; ++i) {
    float bi = b1[ocb + i];
#pragma unroll
    for (int j = 0; j < 4; ++j) acc[i * 4 + j] = bi;
  }
  for (int ci = 0; ci < 64; ++ci) {
    float a0 = Ws[ocb + 0][ci], a1 = Ws[ocb + 1][ci], a2 = Ws[ocb + 2][ci], a3 = Ws[ocb + 3][ci];
    float x0 = Xs[ci][pb + 0], x1 = Xs[ci][pb + 1], x2 = Xs[ci][pb + 2], x3 = Xs[ci][pb + 3];
    acc[0] = fmaf(a0, x0, acc[0]); acc[1] = fmaf(a0, x1, acc[1]);
    acc[2] = fmaf(a0, x2, acc[2]); acc[3] = fmaf(a0, x3, acc[3]);
    acc[4] = fmaf(a1, x0, acc[4]); acc[5] = fmaf(a1, x1, acc[5]);
    acc[6] = fmaf(a1, x2, acc[6]); acc[7] = fmaf(a1, x3, acc[7]);
    acc[8] = fmaf(a2, x0, acc[8]); acc[9] = fmaf(a2, x1, acc[9]);
    acc[10] = fmaf(a2, x2, acc[10]); acc[11] = fmaf(a2, x3, acc[11]);
    acc[12] = fmaf(a3, x0, acc[12]); acc[13] = fmaf(a3, x1, acc[13]);
    acc[14] = fmaf(a3, x2, acc[14]); acc[15] = fmaf(a3, x3, acc[15]);
  }
  __syncthreads();  // all reads of Xs/Ws done
#pragma unroll
  for (int i = 0; i < 4; ++i)
#pragma unroll
    for (int j = 0; j < 4; ++j) Xs[ocb + i][pb + j] = gelu_f(acc[i * 4 + j]);
  for (int i = t; i < 4096; i += 256) Ws[i >> 6][i & 63] = w2[i];
  __syncthreads();
#pragma unroll
  for (int i = 0; i < 4; ++i) {
    float bi = b2[ocb + i];
#pragma unroll
    for (int j = 0; j < 4; ++j) acc[i * 4 + j] = bi;
  }
  for (int ci = 0; ci < 64; ++ci) {
    float a0 = Ws[ocb + 0][ci], a1 = Ws[ocb + 1][ci], a2 = Ws[ocb + 2][ci], a3 = Ws[ocb + 3][ci];
    float x0 = Xs[ci][pb + 0], x1 = Xs[ci][pb + 1], x2 = Xs[ci][pb + 2], x3 = Xs[ci][pb + 3];
    acc[0] = fmaf(a0, x0, acc[0]); acc[1] = fmaf(a0, x1, acc[1]);
    acc[2] = fmaf(a0, x2, acc[2]); acc[3] = fmaf(a0, x3, acc[3]);
    acc[4] = fmaf(a1, x0, acc[4]); acc[5] = fmaf(a1, x1, acc[5]);
    acc[6] = fmaf(a1, x2, acc[6]); acc[7] = fmaf(a1, x3, acc[7]);
    acc[8] = fmaf(a2, x0, acc[8]); acc[9] = fmaf(a2, x1, acc[9]);
    acc[10] = fmaf(a2, x2, acc[10]); acc[11] = fmaf(a2, x3, acc[11]);
    acc[12] = fmaf(a3, x0, acc[12]); acc[13] = fmaf(a3, x1, acc[13]);
    acc[14] = fmaf(a3, x2, acc[14]); acc[15] = fmaf(a3, x3, acc[15]);
  }
#pragma unroll
  for (int i = 0; i < 4; ++i) {
    float4* dst = (float4*)&uio[(size_t)(ocb + i) * HW + p0 + pb];
    float4 u = *dst;
    u.x += gelu_f(acc[i * 4 + 0]);
    u.y += gelu_f(acc[i * 4 + 1]);
    u.z += gelu_f(acc[i * 4 + 2]);
    u.w += gelu_f(acc[i * 4 + 3]);
    *dst = u;
  }
}

__global__ __launch_bounds__(256) void kdecf(const float* __restrict__ ua, const float* __restrict__ w,
                                             const float* __restrict__ b, float* __restrict__ out) {
  int p = blockIdx.x * 256 + threadIdx.x;
  float a0 = b[0], a1 = b[1];
  for (int c = 0; c < 64; ++c) {
    float xv = ua[(size_t)c * 262144 + p];
    a0 = fmaf(w[c], xv, a0);
    a1 = fmaf(w[64 + c], xv, a1);
  }
  out[p] = a0;
  out[262144 + p] = a1;
}

__global__ __launch_bounds__(256) void kcopyf(const float* __restrict__ src, float* __restrict__ out) {
  int p = blockIdx.x * 256 + threadIdx.x;
  out[p] = src[p];
}

extern "C" void kernel_launch(void* const* d_in, const int* in_sizes, int n_in,
                              void* d_out, int out_size, void* d_ws, size_t ws_size,
                              hipStream_t stream) {
  (void)in_sizes; (void)n_in; (void)out_size;
  const float* u_a = (const float*)d_in[0];
  const float* x_a = (const float*)d_in[1];
  const float* u_b = (const float*)d_in[2];
  const float* x_b = (const float*)d_in[3];
  const float* enc_a_w = (const float*)d_in[4];
  const float* enc_a_b = (const float*)d_in[5];
  const float* enc_b_w = (const float*)d_in[6];
  const float* enc_b_b = (const float*)d_in[7];
  const float* dec_w = (const float*)d_in[8];
  const float* dec_b = (const float*)d_in[9];
  const float* c1a_w = (const float*)d_in[10];
  const float* c1a_b = (const float*)d_in[11];
  const float* c2a_w = (const float*)d_in[12];
  const float* c2a_b = (const float*)d_in[13];
  const float* c1b_w = (const float*)d_in[14];
  const float* c1b_b = (const float*)d_in[15];
  const float* c2b_w = (const float*)d_in[16];
  const float* c2b_b = (const float*)d_in[17];
  const float* A_re = (const float*)d_in[18];
  const float* A_im = (const float*)d_in[19];

  if (ws_size < (size_t)38798336 * 4) return;

  float* F = (float*)d_ws;
  float* ua = F;
  float* ua_ = F + 16777216;
  float* ub = F + 33554432;
  float* ub_ = F + 34603008;
  float2* GTa = (float2*)(F + 35651584);
  float2* GTb = (float2*)(F + 37748736);
  float2* coef = (float2*)(F + 38273024);
  float2* coef2 = (float2*)(F + 38535168);
  float2* t512 = (float2*)(F + 38797312);
  float* out = (float*)d_out;

  ktab<<<2, 256, 0, stream>>>(t512);

  const float FA = 1.f / 262144.f, FB = 1.f / 16384.f;
  kenc<262144><<<1024, 256, 0, stream>>>(x_a, u_a, enc_a_w, enc_a_b, ua);
  kenc<16384><<<64, 256, 0, stream>>>(x_b, u_b, enc_b_w, enc_b_b, ub);
  for (int l = 0; l < 4; ++l) {
    kfwd1<512, 1><<<4096, 256, 0, stream>>>(ua, GTa, t512, FA);
    kfwd2<512, 1><<<2048, 256, 0, stream>>>(GTa, coef, t512, 0);
    kfwd1<128, 4><<<1024, 256, 0, stream>>>(ub, GTb, t512, FB);
    kfwd2<128, 4><<<2048, 256, 0, stream>>>(GTb, coef, t512, 64);
    int nout = (l < 3) ? 128 : 64;  // layer 3: B outputs unused
    kmix<<<nout * 4, 256, 0, stream>>>(A_re + (size_t)l * 16777216,
                                       A_im + (size_t)l * 16777216, coef, coef2);
    kinv1<512, 1><<<4096, 256, 0, stream>>>(coef2, GTa, t512, 0);
    kinv2<512, 1, 2><<<16384, 256, 0, stream>>>(GTa, ua_, t512);
    kconv<262144><<<4096, 256, 0, stream>>>(ua_, ua, c1a_w + l * 4096, c1a_b + l * 64,
                                            c2a_w + l * 4096, c2a_b + l * 64);
    if (l < 3) {
      kinv1<128, 4><<<1024, 256, 0, stream>>>(coef2, GTb, t512, 64);
      kinv2<128, 4, 8><<<1024, 256, 0, stream>>>(GTb, ub_, t512);
      kconv<16384><<<256, 256, 0, stream>>>(ub_, ub, c1b_w + l * 4096, c1b_b + l * 64,
                                            c2b_w + l * 4096, c2b_b + l * 64);
    }
  }

  // FLOAT32 outputs, reference order: [dec(ua) (2,512,512); ub (64,128,128)]
  kdecf<<<1024, 256, 0, stream>>>(ua, dec_w, dec_b, out);
  kcopyf<<<4096, 256, 0, stream>>>(ub, out + 524288);
}